// Round 1
// baseline (1119.493 us; speedup 1.0000x reference)
//
#include <hip/hip_runtime.h>

#define ODIM 128  // OUT_DIM

// One edge handled by ODIM threads (lane d owns output dim d).
// out[rows[e]][d] += vals[e] * B[cols[e]][d]
__global__ __launch_bounds__(256) void spmm_scatter(
    const int* __restrict__ rows,
    const int* __restrict__ cols,
    const float* __restrict__ vals,
    const float* __restrict__ B,   // [K x ODIM]
    float* __restrict__ out,       // [N x ODIM]
    int nnz) {
  const int edges_per_block = 256 / ODIM;  // 2
  int e = blockIdx.x * edges_per_block + (threadIdx.x / ODIM);
  int d = threadIdx.x & (ODIM - 1);
  if (e >= nnz) return;
  int r = rows[e];
  int c = cols[e];
  float v = vals[e];
  float contrib = v * B[(long)c * ODIM + d];
  atomicAdd(&out[(long)r * ODIM + d], contrib);
}

__global__ __launch_bounds__(256) void relu_inplace(float* __restrict__ p, long n4) {
  long i = (long)blockIdx.x * blockDim.x + threadIdx.x;
  long stride = (long)gridDim.x * blockDim.x;
  float4* p4 = (float4*)p;
  for (long j = i; j < n4; j += stride) {
    float4 v = p4[j];
    v.x = v.x > 0.f ? v.x : 0.f;
    v.y = v.y > 0.f ? v.y : 0.f;
    v.z = v.z > 0.f ? v.z : 0.f;
    v.w = v.w > 0.f ? v.w : 0.f;
    p4[j] = v;
  }
}

extern "C" void kernel_launch(void* const* d_in, const int* in_sizes, int n_in,
                              void* d_out, int out_size, void* d_ws, size_t ws_size,
                              hipStream_t stream) {
  const int*   x_rows   = (const int*)d_in[0];
  const int*   x_cols   = (const int*)d_in[1];
  const float* x_vals   = (const float*)d_in[2];
  const int*   adj_rows = (const int*)d_in[3];
  const int*   adj_cols = (const int*)d_in[4];
  const float* adj_vals = (const float*)d_in[5];
  const float* W        = (const float*)d_in[6];

  const int nnz_x   = in_sizes[0];
  const int nnz_adj = in_sizes[3];

  float* out = (float*)d_out;            // [N_NODES x 128]
  float* xw  = (float*)d_ws;             // [N_NODES x 128] intermediate

  const size_t out_bytes = (size_t)out_size * sizeof(float);

  // Zero the accumulation buffers (required every call: atomics accumulate).
  hipMemsetAsync(xw,  0, out_bytes, stream);
  hipMemsetAsync(out, 0, out_bytes, stream);

  // Step 1: xw = X_sparse @ W
  {
    const int epb = 256 / ODIM;  // 2 edges per block
    int grid = (nnz_x + epb - 1) / epb;
    spmm_scatter<<<grid, 256, 0, stream>>>(x_rows, x_cols, x_vals, W, xw, nnz_x);
  }

  // Step 2: out = A_sparse @ xw
  {
    const int epb = 256 / ODIM;
    int grid = (nnz_adj + epb - 1) / epb;
    spmm_scatter<<<grid, 256, 0, stream>>>(adj_rows, adj_cols, adj_vals, xw, out, nnz_adj);
  }

  // Step 3: ReLU in place over d_out.
  {
    long n4 = (long)out_size / 4;
    int grid = 2048;
    relu_inplace<<<grid, 256, 0, stream>>>(out, n4);
  }
}

// Round 2
// 817.545 us; speedup vs baseline: 1.3693x; 1.3693x over previous
//
#include <hip/hip_runtime.h>

#define ODIM 128  // OUT_DIM

// ---------------- CSR build ----------------

__global__ __launch_bounds__(256) void hist_kernel(
    const int* __restrict__ rows, int nnz, int* __restrict__ cnt) {
  int i = blockIdx.x * blockDim.x + threadIdx.x;
  int stride = gridDim.x * blockDim.x;
  for (; i < nnz; i += stride) atomicAdd(&cnt[rows[i]], 1);
}

// Single-block exclusive scan of cnt[0..n) -> rowptr[0..n]; cnt becomes cursor
// (cnt[i] overwritten with the exclusive prefix, i.e. the row's start offset).
__global__ __launch_bounds__(1024) void scan_kernel(
    int* __restrict__ cnt, int n, int* __restrict__ rowptr) {
  __shared__ int s[1024];
  int tid = threadIdx.x;
  int chunk = (n + 1023) >> 10;
  int start = tid * chunk;
  int end = start + chunk; if (end > n) end = n; if (start > n) start = n;
  int sum = 0;
  for (int i = start; i < end; i++) sum += cnt[i];
  s[tid] = sum;
  __syncthreads();
  for (int off = 1; off < 1024; off <<= 1) {
    int v = (tid >= off) ? s[tid - off] : 0;
    __syncthreads();
    s[tid] += v;
    __syncthreads();
  }
  int run = s[tid] - sum;  // exclusive prefix of this thread's chunk
  for (int i = start; i < end; i++) {
    int c = cnt[i];
    rowptr[i] = run;
    cnt[i] = run;  // cursor init
    run += c;
  }
  if (tid == 1023) rowptr[n] = s[1023];
}

// Scatter edges into CSR order: cv[pos] = (col, val) packed in 8B.
__global__ __launch_bounds__(256) void scatter_kernel(
    const int* __restrict__ rows, const int* __restrict__ cols,
    const float* __restrict__ vals, int nnz,
    int* __restrict__ cursor, uint2* __restrict__ cv) {
  int i = blockIdx.x * blockDim.x + threadIdx.x;
  int stride = gridDim.x * blockDim.x;
  for (; i < nnz; i += stride) {
    int r = rows[i];
    int pos = atomicAdd(&cursor[r], 1);
    cv[pos] = make_uint2((unsigned)cols[i], __float_as_uint(vals[i]));
  }
}

// ---------------- pull SpMM: out[r][d] = sum_e val_e * B[col_e][d] ----------------
// 128 threads per row (lane d owns dim d); 2 rows per 256-thread block.
template <bool RELU>
__global__ __launch_bounds__(256) void pull_kernel(
    const int* __restrict__ rowptr, const uint2* __restrict__ cv,
    const float* __restrict__ B, float* __restrict__ out, int nrows) {
  int d = threadIdx.x & (ODIM - 1);
  int r = blockIdx.x * 2 + (threadIdx.x >> 7);
  if (r >= nrows) return;
  int e = rowptr[r];
  int end = rowptr[r + 1];
  float acc0 = 0.f, acc1 = 0.f;
  for (; e + 1 < end; e += 2) {
    uint2 a = cv[e];
    uint2 b = cv[e + 1];
    acc0 += __uint_as_float(a.y) * B[(size_t)a.x * ODIM + d];
    acc1 += __uint_as_float(b.y) * B[(size_t)b.x * ODIM + d];
  }
  if (e < end) {
    uint2 a = cv[e];
    acc0 += __uint_as_float(a.y) * B[(size_t)a.x * ODIM + d];
  }
  float acc = acc0 + acc1;
  if (RELU) acc = fmaxf(acc, 0.f);
  out[(size_t)r * ODIM + d] = acc;
}

// ---------------- legacy fallback (atomic push) if ws too small ----------------

__global__ __launch_bounds__(256) void spmm_scatter(
    const int* __restrict__ rows, const int* __restrict__ cols,
    const float* __restrict__ vals, const float* __restrict__ B,
    float* __restrict__ out, int nnz) {
  int e = blockIdx.x * 2 + (threadIdx.x >> 7);
  int d = threadIdx.x & (ODIM - 1);
  if (e >= nnz) return;
  atomicAdd(&out[(size_t)rows[e] * ODIM + d],
            vals[e] * B[(size_t)cols[e] * ODIM + d]);
}

__global__ __launch_bounds__(256) void relu_inplace(float* __restrict__ p, long n4) {
  long i = (long)blockIdx.x * blockDim.x + threadIdx.x;
  long stride = (long)gridDim.x * blockDim.x;
  float4* p4 = (float4*)p;
  for (long j = i; j < n4; j += stride) {
    float4 v = p4[j];
    v.x = fmaxf(v.x, 0.f); v.y = fmaxf(v.y, 0.f);
    v.z = fmaxf(v.z, 0.f); v.w = fmaxf(v.w, 0.f);
    p4[j] = v;
  }
}

extern "C" void kernel_launch(void* const* d_in, const int* in_sizes, int n_in,
                              void* d_out, int out_size, void* d_ws, size_t ws_size,
                              hipStream_t stream) {
  const int*   x_rows   = (const int*)d_in[0];
  const int*   x_cols   = (const int*)d_in[1];
  const float* x_vals   = (const float*)d_in[2];
  const int*   adj_rows = (const int*)d_in[3];
  const int*   adj_cols = (const int*)d_in[4];
  const float* adj_vals = (const float*)d_in[5];
  const float* W        = (const float*)d_in[6];

  const int nnz_x   = in_sizes[0];
  const int nnz_adj = in_sizes[3];
  const int N       = out_size / ODIM;  // 50000 nodes

  float* out = (float*)d_out;

  // Workspace layout
  char* p = (char*)d_ws;
  float* xw  = (float*)p;  p += (size_t)N * ODIM * sizeof(float);
  int*   rpX = (int*)p;    p += (size_t)(N + 1) * sizeof(int);
  int*   rpA = (int*)p;    p += (size_t)(N + 1) * sizeof(int);
  int*   curX = (int*)p;   p += (size_t)N * sizeof(int);
  int*   curA = (int*)p;   p += (size_t)N * sizeof(int);
  p = (char*)(((uintptr_t)p + 255) & ~(uintptr_t)255);
  uint2* cvX = (uint2*)p;  p += (size_t)nnz_x * sizeof(uint2);
  uint2* cvA = (uint2*)p;  p += (size_t)nnz_adj * sizeof(uint2);
  size_t need = (size_t)(p - (char*)d_ws);

  if (ws_size < need) {
    // Fallback: atomic push path (needs only xw).
    const size_t out_bytes = (size_t)out_size * sizeof(float);
    hipMemsetAsync(xw, 0, out_bytes, stream);
    hipMemsetAsync(out, 0, out_bytes, stream);
    spmm_scatter<<<(nnz_x + 1) / 2, 256, 0, stream>>>(x_rows, x_cols, x_vals, W, xw, nnz_x);
    spmm_scatter<<<(nnz_adj + 1) / 2, 256, 0, stream>>>(adj_rows, adj_cols, adj_vals, xw, out, nnz_adj);
    relu_inplace<<<2048, 256, 0, stream>>>(out, (long)out_size / 4);
    return;
  }

  // Zero the histograms/cursors.
  hipMemsetAsync(curX, 0, (size_t)N * sizeof(int), stream);
  hipMemsetAsync(curA, 0, (size_t)N * sizeof(int), stream);

  // Histogram row degrees.
  hist_kernel<<<2048, 256, 0, stream>>>(x_rows, nnz_x, curX);
  hist_kernel<<<2048, 256, 0, stream>>>(adj_rows, nnz_adj, curA);

  // Exclusive scan -> rowptr; cursors initialized to row starts.
  scan_kernel<<<1, 1024, 0, stream>>>(curX, N, rpX);
  scan_kernel<<<1, 1024, 0, stream>>>(curA, N, rpA);

  // Scatter edges into CSR slots.
  scatter_kernel<<<2048, 256, 0, stream>>>(x_rows, x_cols, x_vals, nnz_x, curX, cvX);
  scatter_kernel<<<2048, 256, 0, stream>>>(adj_rows, adj_cols, adj_vals, nnz_adj, curA, cvA);

  // Pull step 1: xw = X @ W   (W is L2-resident, 2.56 MB)
  pull_kernel<false><<<(N + 1) / 2, 256, 0, stream>>>(rpX, cvX, W, xw, N);

  // Pull step 2: out = relu(A @ xw)   (xw is L3-resident, 25.6 MB)
  pull_kernel<true><<<(N + 1) / 2, 256, 0, stream>>>(rpA, cvA, xw, out, N);
}

// Round 5
// 567.888 us; speedup vs baseline: 1.9713x; 1.4396x over previous
//
#include <hip/hip_runtime.h>

#define ODIM 128  // OUT_DIM
#define NLANE 64  // one wave per row; each lane owns 2 dims

// ---------------- fused CSR build ----------------

__global__ __launch_bounds__(256) void hist_both(
    const int* __restrict__ xr, int nx, int* __restrict__ cntX,
    const int* __restrict__ ar, int na, int* __restrict__ cntA) {
  int i = blockIdx.x * blockDim.x + threadIdx.x;
  int stride = gridDim.x * blockDim.x;
  int total = nx + na;
  for (; i < total; i += stride) {
    if (i < nx) atomicAdd(&cntX[xr[i]], 1);
    else        atomicAdd(&cntA[ar[i - nx]], 1);
  }
}

// block 0 scans cntX -> rpX, block 1 scans cntA -> rpA.
// cnt[i] is overwritten with the exclusive prefix (cursor init).
__global__ __launch_bounds__(1024) void scan_both(
    int* __restrict__ cntX, int* __restrict__ rpX,
    int* __restrict__ cntA, int* __restrict__ rpA, int n) {
  int* cnt = (blockIdx.x == 0) ? cntX : cntA;
  int* rp  = (blockIdx.x == 0) ? rpX  : rpA;
  __shared__ int s[1024];
  int tid = threadIdx.x;
  int chunk = (n + 1023) >> 10;
  int start = tid * chunk; if (start > n) start = n;
  int end = start + chunk; if (end > n) end = n;
  int sum = 0;
  for (int i = start; i < end; i++) sum += cnt[i];
  s[tid] = sum;
  __syncthreads();
  for (int off = 1; off < 1024; off <<= 1) {
    int v = (tid >= off) ? s[tid - off] : 0;
    __syncthreads();
    s[tid] += v;
    __syncthreads();
  }
  int run = s[tid] - sum;  // exclusive prefix of this thread's chunk
  for (int i = start; i < end; i++) {
    int c = cnt[i];
    rp[i] = run;
    cnt[i] = run;
    run += c;
  }
  if (tid == 1023) rp[n] = s[1023];
}

__global__ __launch_bounds__(256) void scatter_both(
    const int* __restrict__ xr, const int* __restrict__ xc,
    const float* __restrict__ xv, int nx,
    int* __restrict__ curX, uint2* __restrict__ cvX,
    const int* __restrict__ ar, const int* __restrict__ ac,
    const float* __restrict__ av, int na,
    int* __restrict__ curA, uint2* __restrict__ cvA) {
  int i = blockIdx.x * blockDim.x + threadIdx.x;
  int stride = gridDim.x * blockDim.x;
  int total = nx + na;
  for (; i < total; i += stride) {
    if (i < nx) {
      int pos = atomicAdd(&curX[xr[i]], 1);
      cvX[pos] = make_uint2((unsigned)xc[i], __float_as_uint(xv[i]));
    } else {
      int j = i - nx;
      int pos = atomicAdd(&curA[ar[j]], 1);
      cvA[pos] = make_uint2((unsigned)ac[j], __float_as_uint(av[j]));
    }
  }
}

// ---------------- pulls ----------------

__device__ inline unsigned f2bf(float x) {  // fp32 -> bf16 bits, RNE
  unsigned u = __float_as_uint(x);
  return (u + 0x7fffu + ((u >> 16) & 1u)) >> 16;
}

// xw[r] = sum_e val_e * W[col_e]  (W fp32, L2-resident; xw stored bf16-packed)
__global__ __launch_bounds__(256) void pull_x(
    const int* __restrict__ rowptr, const uint2* __restrict__ cv,
    const float* __restrict__ W, unsigned* __restrict__ xw, int nrows) {
  int lane = threadIdx.x & (NLANE - 1);
  int r = blockIdx.x * 4 + (threadIdx.x >> 6);
  if (r >= nrows) return;
  int e = rowptr[r], end = rowptr[r + 1];
  const float2* W2 = (const float2*)W;
  float a0 = 0.f, a1 = 0.f, b0 = 0.f, b1 = 0.f;
  for (; e + 1 < end; e += 2) {
    uint2 ca = cv[e];
    uint2 cb = cv[e + 1];
    float2 wa = W2[(size_t)ca.x * NLANE + lane];
    float2 wb = W2[(size_t)cb.x * NLANE + lane];
    float va = __uint_as_float(ca.y), vb = __uint_as_float(cb.y);
    a0 += va * wa.x; a1 += va * wa.y;
    b0 += vb * wb.x; b1 += vb * wb.y;
  }
  if (e < end) {
    uint2 ca = cv[e];
    float2 wa = W2[(size_t)ca.x * NLANE + lane];
    float va = __uint_as_float(ca.y);
    a0 += va * wa.x; a1 += va * wa.y;
  }
  xw[(size_t)r * NLANE + lane] = f2bf(a0 + b0) | (f2bf(a1 + b1) << 16);
}

// out[r] = relu( sum_e val_e * xw[col_e] )  (xw bf16-packed, out fp32)
__global__ __launch_bounds__(256) void pull_a(
    const int* __restrict__ rowptr, const uint2* __restrict__ cv,
    const unsigned* __restrict__ xw, float2* __restrict__ out, int nrows) {
  int lane = threadIdx.x & (NLANE - 1);
  int r = blockIdx.x * 4 + (threadIdx.x >> 6);
  if (r >= nrows) return;
  int e = rowptr[r], end = rowptr[r + 1];
  float a0 = 0.f, a1 = 0.f, b0 = 0.f, b1 = 0.f;
  for (; e + 1 < end; e += 2) {
    uint2 ca = cv[e];
    uint2 cb = cv[e + 1];
    unsigned ua = xw[(size_t)ca.x * NLANE + lane];
    unsigned ub = xw[(size_t)cb.x * NLANE + lane];
    float va = __uint_as_float(ca.y), vb = __uint_as_float(cb.y);
    a0 += va * __uint_as_float(ua << 16);
    a1 += va * __uint_as_float(ua & 0xffff0000u);
    b0 += vb * __uint_as_float(ub << 16);
    b1 += vb * __uint_as_float(ub & 0xffff0000u);
  }
  if (e < end) {
    uint2 ca = cv[e];
    unsigned ua = xw[(size_t)ca.x * NLANE + lane];
    float va = __uint_as_float(ca.y);
    a0 += va * __uint_as_float(ua << 16);
    a1 += va * __uint_as_float(ua & 0xffff0000u);
  }
  float o0 = fmaxf(a0 + b0, 0.f);
  float o1 = fmaxf(a1 + b1, 0.f);
  out[(size_t)r * NLANE + lane] = make_float2(o0, o1);
}

// ---------------- fallback (atomic push) if ws too small ----------------

__global__ __launch_bounds__(256) void spmm_scatter(
    const int* __restrict__ rows, const int* __restrict__ cols,
    const float* __restrict__ vals, const float* __restrict__ B,
    float* __restrict__ out, int nnz) {
  int e = blockIdx.x * 2 + (threadIdx.x >> 7);
  int d = threadIdx.x & (ODIM - 1);
  if (e >= nnz) return;
  atomicAdd(&out[(size_t)rows[e] * ODIM + d],
            vals[e] * B[(size_t)cols[e] * ODIM + d]);
}

__global__ __launch_bounds__(256) void relu_inplace(float* __restrict__ p, long n4) {
  long i = (long)blockIdx.x * blockDim.x + threadIdx.x;
  long stride = (long)gridDim.x * blockDim.x;
  float4* p4 = (float4*)p;
  for (long j = i; j < n4; j += stride) {
    float4 v = p4[j];
    v.x = fmaxf(v.x, 0.f); v.y = fmaxf(v.y, 0.f);
    v.z = fmaxf(v.z, 0.f); v.w = fmaxf(v.w, 0.f);
    p4[j] = v;
  }
}

extern "C" void kernel_launch(void* const* d_in, const int* in_sizes, int n_in,
                              void* d_out, int out_size, void* d_ws, size_t ws_size,
                              hipStream_t stream) {
  const int*   x_rows   = (const int*)d_in[0];
  const int*   x_cols   = (const int*)d_in[1];
  const float* x_vals   = (const float*)d_in[2];
  const int*   adj_rows = (const int*)d_in[3];
  const int*   adj_cols = (const int*)d_in[4];
  const float* adj_vals = (const float*)d_in[5];
  const float* W        = (const float*)d_in[6];

  const int nnz_x   = in_sizes[0];
  const int nnz_adj = in_sizes[3];
  const int N       = out_size / ODIM;  // 50000 nodes

  float* out = (float*)d_out;

  // Workspace layout
  char* p = (char*)d_ws;
  unsigned* xw = (unsigned*)p; p += (size_t)N * NLANE * sizeof(unsigned);  // bf16x2-packed
  int* curX = (int*)p;         p += (size_t)N * sizeof(int);
  int* curA = (int*)p;         p += (size_t)N * sizeof(int);  // adjacent to curX: one memset
  int* rpX  = (int*)p;         p += (size_t)(N + 1) * sizeof(int);
  int* rpA  = (int*)p;         p += (size_t)(N + 1) * sizeof(int);
  p = (char*)(((uintptr_t)p + 255) & ~(uintptr_t)255);
  uint2* cvX = (uint2*)p;      p += (size_t)nnz_x * sizeof(uint2);
  uint2* cvA = (uint2*)p;      p += (size_t)nnz_adj * sizeof(uint2);
  size_t need = (size_t)(p - (char*)d_ws);

  if (ws_size < need) {
    // Fallback: atomic push with fp32 xw at start of ws.
    float* xwf = (float*)d_ws;
    const size_t out_bytes = (size_t)out_size * sizeof(float);
    (void)hipMemsetAsync(xwf, 0, out_bytes, stream);
    (void)hipMemsetAsync(out, 0, out_bytes, stream);
    spmm_scatter<<<(nnz_x + 1) / 2, 256, 0, stream>>>(x_rows, x_cols, x_vals, W, xwf, nnz_x);
    spmm_scatter<<<(nnz_adj + 1) / 2, 256, 0, stream>>>(adj_rows, adj_cols, adj_vals, xwf, out, nnz_adj);
    relu_inplace<<<2048, 256, 0, stream>>>(out, (long)out_size / 4);
    return;
  }

  // One memset for both cursor arrays.
  (void)hipMemsetAsync(curX, 0, 2 * (size_t)N * sizeof(int), stream);

  hist_both<<<4096, 256, 0, stream>>>(x_rows, nnz_x, curX, adj_rows, nnz_adj, curA);
  scan_both<<<2, 1024, 0, stream>>>(curX, rpX, curA, rpA, N);
  scatter_both<<<4096, 256, 0, stream>>>(x_rows, x_cols, x_vals, nnz_x, curX, cvX,
                                         adj_rows, adj_cols, adj_vals, nnz_adj, curA, cvA);

  // Step 1: xw = X @ W  (fp32 accumulate, bf16 store)
  pull_x<<<(N + 3) / 4, 256, 0, stream>>>(rpX, cvX, W, xw, N);

  // Step 2: out = relu(A @ xw)
  pull_a<<<(N + 3) / 4, 256, 0, stream>>>(rpA, cvA, xw, (float2*)out, N);
}

// Round 6
// 535.530 us; speedup vs baseline: 2.0904x; 1.0604x over previous
//
#include <hip/hip_runtime.h>

#define ODIM 128  // OUT_DIM
#define NLANE 64  // one wave per row; each lane owns 2 dims

typedef unsigned long long u64;

// ---------------- fused CSR build ----------------

// 4 edges per thread; tail handled by thread 0.
__global__ __launch_bounds__(256) void hist_both(
    const int* __restrict__ xr, int nx, int* __restrict__ cntX,
    const int* __restrict__ ar, int na, int* __restrict__ cntA) {
  int nx4 = nx >> 2, na4 = na >> 2;
  int total4 = nx4 + na4;
  int i = blockIdx.x * blockDim.x + threadIdx.x;
  int stride = gridDim.x * blockDim.x;
  for (int t = i; t < total4; t += stride) {
    if (t < nx4) {
      int4 r4 = ((const int4*)xr)[t];
      atomicAdd(&cntX[r4.x], 1); atomicAdd(&cntX[r4.y], 1);
      atomicAdd(&cntX[r4.z], 1); atomicAdd(&cntX[r4.w], 1);
    } else {
      int4 r4 = ((const int4*)ar)[t - nx4];
      atomicAdd(&cntA[r4.x], 1); atomicAdd(&cntA[r4.y], 1);
      atomicAdd(&cntA[r4.z], 1); atomicAdd(&cntA[r4.w], 1);
    }
  }
  if (i == 0) {
    for (int j = nx4 << 2; j < nx; ++j) atomicAdd(&cntX[xr[j]], 1);
    for (int j = na4 << 2; j < na; ++j) atomicAdd(&cntA[ar[j]], 1);
  }
}

// block 0 scans cntX -> rpX, block 1 scans cntA -> rpA.
// cnt[i] is overwritten with the exclusive prefix (cursor init).
__global__ __launch_bounds__(1024) void scan_both(
    int* __restrict__ cntX, int* __restrict__ rpX,
    int* __restrict__ cntA, int* __restrict__ rpA, int n) {
  int* cnt = (blockIdx.x == 0) ? cntX : cntA;
  int* rp  = (blockIdx.x == 0) ? rpX  : rpA;
  __shared__ int s[1024];
  int tid = threadIdx.x;
  int chunk = (n + 1023) >> 10;
  int start = tid * chunk; if (start > n) start = n;
  int end = start + chunk; if (end > n) end = n;
  int sum = 0;
  for (int i = start; i < end; i++) sum += cnt[i];
  s[tid] = sum;
  __syncthreads();
  for (int off = 1; off < 1024; off <<= 1) {
    int v = (tid >= off) ? s[tid - off] : 0;
    __syncthreads();
    s[tid] += v;
    __syncthreads();
  }
  int run = s[tid] - sum;  // exclusive prefix of this thread's chunk
  for (int i = start; i < end; i++) {
    int c = cnt[i];
    rp[i] = run;
    cnt[i] = run;
    run += c;
  }
  if (tid == 1023) rp[n] = s[1023];
}

__device__ inline void scat1(int r, int c, float v, int* cur, u64* cv) {
  int pos = atomicAdd(&cur[r], 1);
  u64 packed = (u64)(unsigned)c | ((u64)__float_as_uint(v) << 32);
  __builtin_nontemporal_store(packed, &cv[pos]);
}

// 4 edges per thread; nontemporal 8B packed stores (avoid cross-XCD
// partial-dirty-line write amplification). Tail by thread 0.
__global__ __launch_bounds__(256) void scatter_both(
    const int* __restrict__ xr, const int* __restrict__ xc,
    const float* __restrict__ xv, int nx,
    int* __restrict__ curX, u64* __restrict__ cvX,
    const int* __restrict__ ar, const int* __restrict__ ac,
    const float* __restrict__ av, int na,
    int* __restrict__ curA, u64* __restrict__ cvA) {
  int nx4 = nx >> 2, na4 = na >> 2;
  int total4 = nx4 + na4;
  int i = blockIdx.x * blockDim.x + threadIdx.x;
  int stride = gridDim.x * blockDim.x;
  for (int t = i; t < total4; t += stride) {
    const int *rows, *cols; const float* vals; int* cur; u64* cv; int base;
    if (t < nx4) { rows = xr; cols = xc; vals = xv; cur = curX; cv = cvX; base = t << 2; }
    else { rows = ar; cols = ac; vals = av; cur = curA; cv = cvA; base = (t - nx4) << 2; }
    int4   r4 = ((const int4*)(rows + base))[0];
    int4   c4 = ((const int4*)(cols + base))[0];
    float4 v4 = ((const float4*)(vals + base))[0];
    scat1(r4.x, c4.x, v4.x, cur, cv);
    scat1(r4.y, c4.y, v4.y, cur, cv);
    scat1(r4.z, c4.z, v4.z, cur, cv);
    scat1(r4.w, c4.w, v4.w, cur, cv);
  }
  if (i == 0) {
    for (int j = nx4 << 2; j < nx; ++j) scat1(xr[j], xc[j], xv[j], curX, cvX);
    for (int j = na4 << 2; j < na; ++j) scat1(ar[j], ac[j], av[j], curA, cvA);
  }
}

// ---------------- pulls ----------------

__device__ inline unsigned f2bf(float x) {  // fp32 -> bf16 bits, RNE
  unsigned u = __float_as_uint(x);
  return (u + 0x7fffu + ((u >> 16) & 1u)) >> 16;
}

// xw[r] = sum_e val_e * W[col_e]  (W fp32, L2-resident; xw stored bf16-packed)
__global__ __launch_bounds__(256) void pull_x(
    const int* __restrict__ rowptr, const uint2* __restrict__ cv,
    const float* __restrict__ W, unsigned* __restrict__ xw, int nrows) {
  int lane = threadIdx.x & (NLANE - 1);
  int r = blockIdx.x * 4 + (threadIdx.x >> 6);
  if (r >= nrows) return;
  int e = rowptr[r], end = rowptr[r + 1];
  const float2* W2 = (const float2*)W;
  float a0 = 0.f, a1 = 0.f, b0 = 0.f, b1 = 0.f;
  for (; e + 1 < end; e += 2) {
    uint2 ca = cv[e];
    uint2 cb = cv[e + 1];
    float2 wa = W2[(size_t)ca.x * NLANE + lane];
    float2 wb = W2[(size_t)cb.x * NLANE + lane];
    float va = __uint_as_float(ca.y), vb = __uint_as_float(cb.y);
    a0 += va * wa.x; a1 += va * wa.y;
    b0 += vb * wb.x; b1 += vb * wb.y;
  }
  if (e < end) {
    uint2 ca = cv[e];
    float2 wa = W2[(size_t)ca.x * NLANE + lane];
    float va = __uint_as_float(ca.y);
    a0 += va * wa.x; a1 += va * wa.y;
  }
  xw[(size_t)r * NLANE + lane] = f2bf(a0 + b0) | (f2bf(a1 + b1) << 16);
}

// out[r] = relu( sum_e val_e * xw[col_e] )  (xw bf16-packed, out fp32)
// 4-edge unroll: 4 independent 256B gathers in flight per wave.
__global__ __launch_bounds__(256) void pull_a(
    const int* __restrict__ rowptr, const uint2* __restrict__ cv,
    const unsigned* __restrict__ xw, float2* __restrict__ out, int nrows) {
  int lane = threadIdx.x & (NLANE - 1);
  int r = blockIdx.x * 4 + (threadIdx.x >> 6);
  if (r >= nrows) return;
  int e = rowptr[r], end = rowptr[r + 1];
  float a0 = 0.f, a1 = 0.f, b0 = 0.f, b1 = 0.f;
  float c0 = 0.f, c1 = 0.f, d0 = 0.f, d1 = 0.f;
  for (; e + 3 < end; e += 4) {
    uint2 ca = cv[e];
    uint2 cb = cv[e + 1];
    uint2 cc = cv[e + 2];
    uint2 cd = cv[e + 3];
    unsigned ua = xw[(size_t)ca.x * NLANE + lane];
    unsigned ub = xw[(size_t)cb.x * NLANE + lane];
    unsigned uc = xw[(size_t)cc.x * NLANE + lane];
    unsigned ud = xw[(size_t)cd.x * NLANE + lane];
    float va = __uint_as_float(ca.y), vb = __uint_as_float(cb.y);
    float vc = __uint_as_float(cc.y), vd = __uint_as_float(cd.y);
    a0 += va * __uint_as_float(ua << 16);
    a1 += va * __uint_as_float(ua & 0xffff0000u);
    b0 += vb * __uint_as_float(ub << 16);
    b1 += vb * __uint_as_float(ub & 0xffff0000u);
    c0 += vc * __uint_as_float(uc << 16);
    c1 += vc * __uint_as_float(uc & 0xffff0000u);
    d0 += vd * __uint_as_float(ud << 16);
    d1 += vd * __uint_as_float(ud & 0xffff0000u);
  }
  for (; e < end; ++e) {
    uint2 ca = cv[e];
    unsigned ua = xw[(size_t)ca.x * NLANE + lane];
    float va = __uint_as_float(ca.y);
    a0 += va * __uint_as_float(ua << 16);
    a1 += va * __uint_as_float(ua & 0xffff0000u);
  }
  float o0 = fmaxf((a0 + b0) + (c0 + d0), 0.f);
  float o1 = fmaxf((a1 + b1) + (c1 + d1), 0.f);
  out[(size_t)r * NLANE + lane] = make_float2(o0, o1);
}

// ---------------- fallback (atomic push) if ws too small ----------------

__global__ __launch_bounds__(256) void spmm_scatter(
    const int* __restrict__ rows, const int* __restrict__ cols,
    const float* __restrict__ vals, const float* __restrict__ B,
    float* __restrict__ out, int nnz) {
  int e = blockIdx.x * 2 + (threadIdx.x >> 7);
  int d = threadIdx.x & (ODIM - 1);
  if (e >= nnz) return;
  atomicAdd(&out[(size_t)rows[e] * ODIM + d],
            vals[e] * B[(size_t)cols[e] * ODIM + d]);
}

__global__ __launch_bounds__(256) void relu_inplace(float* __restrict__ p, long n4) {
  long i = (long)blockIdx.x * blockDim.x + threadIdx.x;
  long stride = (long)gridDim.x * blockDim.x;
  float4* p4 = (float4*)p;
  for (long j = i; j < n4; j += stride) {
    float4 v = p4[j];
    v.x = fmaxf(v.x, 0.f); v.y = fmaxf(v.y, 0.f);
    v.z = fmaxf(v.z, 0.f); v.w = fmaxf(v.w, 0.f);
    p4[j] = v;
  }
}

extern "C" void kernel_launch(void* const* d_in, const int* in_sizes, int n_in,
                              void* d_out, int out_size, void* d_ws, size_t ws_size,
                              hipStream_t stream) {
  const int*   x_rows   = (const int*)d_in[0];
  const int*   x_cols   = (const int*)d_in[1];
  const float* x_vals   = (const float*)d_in[2];
  const int*   adj_rows = (const int*)d_in[3];
  const int*   adj_cols = (const int*)d_in[4];
  const float* adj_vals = (const float*)d_in[5];
  const float* W        = (const float*)d_in[6];

  const int nnz_x   = in_sizes[0];
  const int nnz_adj = in_sizes[3];
  const int N       = out_size / ODIM;  // 50000 nodes

  float* out = (float*)d_out;

  // Workspace layout
  char* p = (char*)d_ws;
  unsigned* xw = (unsigned*)p; p += (size_t)N * NLANE * sizeof(unsigned);  // bf16x2-packed
  int* curX = (int*)p;         p += (size_t)N * sizeof(int);
  int* curA = (int*)p;         p += (size_t)N * sizeof(int);  // adjacent to curX: one memset
  int* rpX  = (int*)p;         p += (size_t)(N + 1) * sizeof(int);
  int* rpA  = (int*)p;         p += (size_t)(N + 1) * sizeof(int);
  p = (char*)(((uintptr_t)p + 255) & ~(uintptr_t)255);
  u64* cvX = (u64*)p;          p += (size_t)nnz_x * sizeof(u64);
  u64* cvA = (u64*)p;          p += (size_t)nnz_adj * sizeof(u64);
  size_t need = (size_t)(p - (char*)d_ws);

  if (ws_size < need) {
    // Fallback: atomic push with fp32 xw at start of ws.
    float* xwf = (float*)d_ws;
    const size_t out_bytes = (size_t)out_size * sizeof(float);
    (void)hipMemsetAsync(xwf, 0, out_bytes, stream);
    (void)hipMemsetAsync(out, 0, out_bytes, stream);
    spmm_scatter<<<(nnz_x + 1) / 2, 256, 0, stream>>>(x_rows, x_cols, x_vals, W, xwf, nnz_x);
    spmm_scatter<<<(nnz_adj + 1) / 2, 256, 0, stream>>>(adj_rows, adj_cols, adj_vals, xwf, out, nnz_adj);
    relu_inplace<<<2048, 256, 0, stream>>>(out, (long)out_size / 4);
    return;
  }

  // One memset for both cursor arrays.
  (void)hipMemsetAsync(curX, 0, 2 * (size_t)N * sizeof(int), stream);

  hist_both<<<2048, 256, 0, stream>>>(x_rows, nnz_x, curX, adj_rows, nnz_adj, curA);
  scan_both<<<2, 1024, 0, stream>>>(curX, rpX, curA, rpA, N);
  scatter_both<<<2048, 256, 0, stream>>>(x_rows, x_cols, x_vals, nnz_x, curX, cvX,
                                         adj_rows, adj_cols, adj_vals, nnz_adj, curA, cvA);

  // Step 1: xw = X @ W  (fp32 accumulate, bf16 store)
  pull_x<<<(N + 3) / 4, 256, 0, stream>>>(rpX, (const uint2*)cvX, W, xw, N);

  // Step 2: out = relu(A @ xw)
  pull_a<<<(N + 3) / 4, 256, 0, stream>>>(rpA, (const uint2*)cvA, xw, (float2*)out, N);
}